// Round 11
// baseline (173.393 us; speedup 1.0000x reference)
//
#include <hip/hip_runtime.h>
#include <hip/hip_bf16.h>
#include <math.h>

// Problem constants
#define BROWS 16384
#define IN_DIM 128
#define HID 512
#define ATT 256
#define KTOT 896          // IN_DIM + HID + ATT
#define KC_TOT 112        // KTOT / 8

typedef __bf16 bf16x8 __attribute__((ext_vector_type(8)));
typedef float f32x4 __attribute__((ext_vector_type(4)));

// ---------------------------------------------------------------------------
// Kernel 1: pack augmented weights -> B_stage[jt(8)][kc(112)][nl(192)][8] bf16.
// nl = jg*48 + type*16 + j16 ; jg in [0,4), type 0=gate 1=dyn 2=tau.
// j = jt*64 + jg*16 + j16. tau rows ZERO outside k in [128,640).
// ---------------------------------------------------------------------------
__device__ __forceinline__ float softplus_f(float x) {
    return fmaxf(x, 0.0f) + log1pf(__expf(-fabsf(x)));
}

__global__ void pack_B(const float* __restrict__ W_gd, const float* __restrict__ W_tau,
                       const float* __restrict__ gleak, const float* __restrict__ cm,
                       __hip_bfloat16* __restrict__ B_stage, float* __restrict__ dconst) {
    const int cid = blockIdx.x * 256 + threadIdx.x;   // 672*256 = 172032 = 8*112*192
    if (cid < HID) {
        dconst[cid] = softplus_f(cm[cid]) + softplus_f(gleak[cid]) + 1e-6f;
    }
    const int nl = cid % 192;
    const int kc = (cid / 192) % KC_TOT;
    const int jt = cid / (192 * KC_TOT);
    const int jg = nl / 48, type = (nl % 48) / 16, j16 = nl % 16;
    const int j = jt * 64 + jg * 16 + j16;
    const int k0 = kc * 8;

    float v[8];
    if (type == 0) {
        const float* s = W_gd + (size_t)j * KTOT + k0;
        #pragma unroll
        for (int i = 0; i < 8; ++i) v[i] = s[i];
    } else if (type == 1) {
        const float* s = W_gd + (size_t)(HID + j) * KTOT + k0;
        #pragma unroll
        for (int i = 0; i < 8; ++i) v[i] = s[i];
    } else {
        if (k0 >= IN_DIM && k0 < IN_DIM + HID) {
            const float* s = W_tau + (size_t)j * HID + (k0 - IN_DIM);
            #pragma unroll
            for (int i = 0; i < 8; ++i) v[i] = s[i];
        } else {
            #pragma unroll
            for (int i = 0; i < 8; ++i) v[i] = 0.0f;
        }
    }
    union { __hip_bfloat16 hh[8]; uint4 u; } p;
    #pragma unroll
    for (int i = 0; i < 8; ++i) p.hh[i] = __float2bfloat16(v[i]);
    *(uint4*)(B_stage + (size_t)cid * 8) = p.u;
}

// ---------------------------------------------------------------------------
// Kernel 2: R11 = R10 resubmit (second infra failure on this source; no data).
// This is the EXACT R2 kernel (passed @68.4us, VGPR 120, no spill,
// acc[4][3] + ab[4][4] + bb[4][3], all 64 rows covered by epilogue f<4)
// with ONE variable added: NONTEMPORAL on the single-use streams.
// Theory: R0-R8 invariant 64-68us = ~1300 stall cyc/K-step = L3-class
// latency on B. Streams (A-stage 56MB + h re-read 33MB + out 33MB) thrash
// the 4MB/XCD L2 and evict the 2.75MB B_stage; B re-reads fall to L3,
// invisible in FETCH_SIZE (L3 absorbs). nt bit keeps streams out of L2;
// B_stage stays L2-resident (~200cyc hits, covered by MFMA burst).
// Prediction: pass; dur 45-55us (null >=64us falsifies -> pivot to
// cooperative LDS-staged B). MfmaUtil 28-35%, FETCH ~53MB, WRITE ~32.7MB,
// VGPR ~120, conflicts 0.
// ---------------------------------------------------------------------------
__global__ __launch_bounds__(512, 2) void ltc_gemm(
    const float* __restrict__ x, const float* __restrict__ h_ltc,
    const float* __restrict__ ctx, const __hip_bfloat16* __restrict__ B_stage,
    const float* __restrict__ b_gd, const float* __restrict__ b_tau,
    const float* __restrict__ dconst, float* __restrict__ out) {

    __shared__ __attribute__((aligned(16))) char As[114688];  // [kc 112][mi 64] 16B

    const int mt = blockIdx.x;          // 0..255 : rows mt*64 .. mt*64+63
    const int tid = threadIdx.x;
    const int wave = tid >> 6, lane = tid & 63;
    const int q = lane >> 4, t = lane & 15;

    // ---- Stage A (fp32 -> bf16) once. thread (mi0,kcg) stages 2 halves x 7. ----
    // NONTEMPORAL: these 56MB are read exactly once — do not allocate in L2.
    const int mi0 = tid >> 4;           // 0..31
    const int kcg = tid & 15;           // 0..15
    #pragma unroll
    for (int h = 0; h < 2; ++h) {
        const int mi = mi0 + 32 * h;
        #pragma unroll
        for (int s = 0; s < 7; ++s) {
            const int kc = kcg + 16 * s;
            const float* src; int rs, col;
            if (s == 0)      { src = x;     rs = IN_DIM; col = kcg * 8; }
            else if (s < 5)  { src = h_ltc; rs = HID;    col = kcg * 8 + (s - 1) * 128; }
            else             { src = ctx;   rs = ATT;    col = kcg * 8 + (s - 5) * 128; }
            const float* p = src + (size_t)(mt * 64 + mi) * rs + col;
            f32x4 v0 = __builtin_nontemporal_load((const f32x4*)p);
            f32x4 v1 = __builtin_nontemporal_load((const f32x4*)p + 1);
            union { __hip_bfloat16 hh[8]; uint4 u; } pk;
            pk.hh[0] = __float2bfloat16(v0[0]); pk.hh[1] = __float2bfloat16(v0[1]);
            pk.hh[2] = __float2bfloat16(v0[2]); pk.hh[3] = __float2bfloat16(v0[3]);
            pk.hh[4] = __float2bfloat16(v1[0]); pk.hh[5] = __float2bfloat16(v1[1]);
            pk.hh[6] = __float2bfloat16(v1[2]); pk.hh[7] = __float2bfloat16(v1[3]);
            *(uint4*)(As + ((kc * 64 + (mi ^ (kc & 31))) << 4)) = pk.u;
        }
    }
    __syncthreads();   // the ONLY barrier in this kernel

    // ---- j-loop: 4 iters x (8 waves x 16 j) covers all 512 j ----
    for (int it = 0; it < 4; ++it) {
        const int jglob = it * 128 + wave * 16;       // this wave's j base
        const int jt = jglob >> 6;                    // 0..7
        const int jg = (jglob >> 4) & 3;              // 0..3
        const __hip_bfloat16* bBase = B_stage
            + ((size_t)jt * (KC_TOT * 192) + jg * 48 + t) * 8;

        f32x4 acc[4][3];
        #pragma unroll
        for (int f = 0; f < 4; ++f)
            #pragma unroll
            for (int ty = 0; ty < 3; ++ty) acc[f][ty] = (f32x4)0.0f;

        // deep register pipelines (no barriers, no spills):
        // ab ring-4 @ distance 2 (LDS), bb ring-4 @ distance 3 (L2)
        bf16x8 ab[4][4]; bf16x8 bb[4][3];

        // prologue: A for steps 0,1 ; B for steps 0,1,2 (tau starts at step 4)
        #pragma unroll
        for (int p = 0; p < 2; ++p) {
            const int kc = p * 4 + q;
            const int sw = kc & 31;
            ab[p][0] = *(const bf16x8*)(As + ((kc * 64 + (t ^ sw)) << 4));
            ab[p][1] = *(const bf16x8*)(As + ((kc * 64 + ((16 + t) ^ sw)) << 4));
            ab[p][2] = *(const bf16x8*)(As + ((kc * 64 + ((32 + t) ^ sw)) << 4));
            ab[p][3] = *(const bf16x8*)(As + ((kc * 64 + ((48 + t) ^ sw)) << 4));
        }
        #pragma unroll
        for (int p = 0; p < 3; ++p) {
            const __hip_bfloat16* bp = bBase + (size_t)(p * 4 + q) * 1536;
            bb[p][0] = *(const bf16x8*)(bp);
            bb[p][1] = *(const bf16x8*)(bp + 128);
        }

        #pragma unroll 4
        for (int kst = 0; kst < 28; ++kst) {
            const int ca = kst & 3;
            // issue next loads first — they retire while we MFMA
            if (kst < 26) {            // A prefetch, distance 2
                const int kc = (kst + 2) * 4 + q;
                const int sw = kc & 31;
                const int na = (kst + 2) & 3;
                ab[na][0] = *(const bf16x8*)(As + ((kc * 64 + (t ^ sw)) << 4));
                ab[na][1] = *(const bf16x8*)(As + ((kc * 64 + ((16 + t) ^ sw)) << 4));
                ab[na][2] = *(const bf16x8*)(As + ((kc * 64 + ((32 + t) ^ sw)) << 4));
                ab[na][3] = *(const bf16x8*)(As + ((kc * 64 + ((48 + t) ^ sw)) << 4));
            }
            if (kst < 25) {            // B prefetch, distance 3
                const int kc = (kst + 3) * 4 + q;
                const int nbf = (kst + 3) & 3;
                const __hip_bfloat16* bp = bBase + (size_t)kc * 1536;
                bb[nbf][0] = *(const bf16x8*)(bp);
                bb[nbf][1] = *(const bf16x8*)(bp + 128);
                if (kst + 3 >= 4 && kst + 3 < 20)
                    bb[nbf][2] = *(const bf16x8*)(bp + 256);
            }
            const bool tau_cur = (kst >= 4 && kst < 20);   // k in [128,640)
            acc[0][0] = __builtin_amdgcn_mfma_f32_16x16x32_bf16(ab[ca][0], bb[ca][0], acc[0][0], 0, 0, 0);
            acc[1][0] = __builtin_amdgcn_mfma_f32_16x16x32_bf16(ab[ca][1], bb[ca][0], acc[1][0], 0, 0, 0);
            acc[2][0] = __builtin_amdgcn_mfma_f32_16x16x32_bf16(ab[ca][2], bb[ca][0], acc[2][0], 0, 0, 0);
            acc[3][0] = __builtin_amdgcn_mfma_f32_16x16x32_bf16(ab[ca][3], bb[ca][0], acc[3][0], 0, 0, 0);
            acc[0][1] = __builtin_amdgcn_mfma_f32_16x16x32_bf16(ab[ca][0], bb[ca][1], acc[0][1], 0, 0, 0);
            acc[1][1] = __builtin_amdgcn_mfma_f32_16x16x32_bf16(ab[ca][1], bb[ca][1], acc[1][1], 0, 0, 0);
            acc[2][1] = __builtin_amdgcn_mfma_f32_16x16x32_bf16(ab[ca][2], bb[ca][1], acc[2][1], 0, 0, 0);
            acc[3][1] = __builtin_amdgcn_mfma_f32_16x16x32_bf16(ab[ca][3], bb[ca][1], acc[3][1], 0, 0, 0);
            if (tau_cur) {
                acc[0][2] = __builtin_amdgcn_mfma_f32_16x16x32_bf16(ab[ca][0], bb[ca][2], acc[0][2], 0, 0, 0);
                acc[1][2] = __builtin_amdgcn_mfma_f32_16x16x32_bf16(ab[ca][1], bb[ca][2], acc[1][2], 0, 0, 0);
                acc[2][2] = __builtin_amdgcn_mfma_f32_16x16x32_bf16(ab[ca][2], bb[ca][2], acc[2][2], 0, 0, 0);
                acc[3][2] = __builtin_amdgcn_mfma_f32_16x16x32_bf16(ab[ca][3], bb[ca][2], acc[3][2], 0, 0, 0);
            }
        }

        // ---- epilogue for this wave's 64 rows x 16 j ----
        // NONTEMPORAL: h re-read (33MB) and out store (33MB) are single-use.
        const int j = jglob + t;
        const float bgj = b_gd[j];
        const float bdj = b_gd[HID + j];
        const float btj = b_tau[j];
        const float dcj = dconst[j];
        #pragma unroll
        for (int f = 0; f < 4; ++f) {
            #pragma unroll
            for (int r = 0; r < 4; ++r) {
                const int row = mt * 64 + f * 16 + q * 4 + r;
                const float gv = acc[f][0][r] + bgj;
                const float dv = acc[f][1][r] + bdj;
                const float tp = acc[f][2][r] + btj;
                const float hv = __builtin_nontemporal_load(&h_ltc[(size_t)row * HID + j]);
                const float sig = __builtin_amdgcn_rcpf(1.0f + __expf(-gv));
                const float th  = 1.0f - 2.0f * __builtin_amdgcn_rcpf(__expf(2.0f * dv) + 1.0f);
                const float tau = fmaxf(tp, 0.0f) + __logf(1.0f + __expf(-fabsf(tp)));
                const float res = (sig * th - hv) * __builtin_amdgcn_rcpf(tau + dcj);
                __builtin_nontemporal_store(res, &out[(size_t)row * HID + j]);
            }
        }
    }
}

// ---------------------------------------------------------------------------
extern "C" void kernel_launch(void* const* d_in, const int* in_sizes, int n_in,
                              void* d_out, int out_size, void* d_ws, size_t ws_size,
                              hipStream_t stream) {
    // setup_inputs order: t, h_ltc, x_t, context, W_gd, b_gd, W_tau, b_tau, gleak, cm
    const float* h_ltc = (const float*)d_in[1];
    const float* x_t   = (const float*)d_in[2];
    const float* ctx   = (const float*)d_in[3];
    const float* W_gd  = (const float*)d_in[4];
    const float* b_gd  = (const float*)d_in[5];
    const float* W_tau = (const float*)d_in[6];
    const float* b_tau = (const float*)d_in[7];
    const float* gleak = (const float*)d_in[8];
    const float* cm    = (const float*)d_in[9];

    char* ws = (char*)d_ws;
    __hip_bfloat16* B_stage = (__hip_bfloat16*)ws;      // 8*112*192*8*2 = 2,752,512 B
    float* dconst = (float*)(ws + 2752512);             // 2,048 B

    pack_B<<<672, 256, 0, stream>>>(W_gd, W_tau, gleak, cm, B_stage, dconst);
    ltc_gemm<<<256, 512, 0, stream>>>(x_t, h_ltc, ctx, B_stage, b_gd, b_tau, dconst,
                                      (float*)d_out);
}